// Round 12
// baseline (225.662 us; speedup 1.0000x reference)
//
#include <hip/hip_runtime.h>

#define IN_F 4096
#define OUT_F 4096
#define M_DIM 8192  // 4 * 2048
#define NTK 64      // K tiles of 64 (i8)

typedef __attribute__((ext_vector_type(4))) int i32x4;

typedef const __attribute__((address_space(1))) void* gas_t;
typedef __attribute__((address_space(3))) void* las_t;

__device__ __forceinline__ void async16(const void* g, void* s) {
  __builtin_amdgcn_global_load_lds((gas_t)g, (las_t)s, 16, 0, 0);
}

// ---- fused prep, 512-thread blocks:
//   blocks [0,4096):    quantize 2 x-rows per block (256 threads each half)
//   blocks [4096,6144): decompress 2048 code-quads per block (4 codes/thread)
// quantize: xq=i8 per-row (s=absmax/127), rs2=128*rowsum (exact f32 term)
// decompress: codes -> packed i8 (w-128 == w^0x80)
__global__ __launch_bounds__(512) void k_prep(
    const float* __restrict__ x, const int* __restrict__ codes,
    const int* __restrict__ table, int* __restrict__ xq,
    float* __restrict__ s, float* __restrict__ rs2, int* __restrict__ Wq) {
  const int bid = blockIdx.x, t = threadIdx.x;
  if (bid >= M_DIM / 2) {  // ---- decompress path
    int i = (bid - M_DIM / 2) * 512 + t;  // quad index
    int4 c = *(const int4*)(codes + (size_t)i * 4);
    int4 t0 = *(const int4*)(table + (size_t)c.x * 4);
    int4 t1 = *(const int4*)(table + (size_t)c.y * 4);
    int4 t2 = *(const int4*)(table + (size_t)c.z * 4);
    int4 t3 = *(const int4*)(table + (size_t)c.w * 4);
    int4 o;
    o.x = (t0.x | (t0.y << 8) | (t0.z << 16) | (t0.w << 24)) ^ 0x80808080;
    o.y = (t1.x | (t1.y << 8) | (t1.z << 16) | (t1.w << 24)) ^ 0x80808080;
    o.z = (t2.x | (t2.y << 8) | (t2.z << 16) | (t2.w << 24)) ^ 0x80808080;
    o.w = (t3.x | (t3.y << 8) | (t3.z << 16) | (t3.w << 24)) ^ 0x80808080;
    *(int4*)(Wq + (size_t)i * 4) = o;
    return;
  }
  // ---- quantize path: half = row parity, 256 threads per row
  __shared__ float2 sred[2][4];
  const int half = t >> 8, tt = t & 255;
  const int row = bid * 2 + half;
  const float4* xr = (const float4*)(x + (size_t)row * IN_F);
  float4 v[4];
  float amax = 0.f, sum = 0.f;
#pragma unroll
  for (int i = 0; i < 4; ++i) {
    v[i] = xr[tt + i * 256];
    amax = fmaxf(amax, fmaxf(fmaxf(fabsf(v[i].x), fabsf(v[i].y)),
                             fmaxf(fabsf(v[i].z), fabsf(v[i].w))));
    sum += v[i].x + v[i].y + v[i].z + v[i].w;
  }
#pragma unroll
  for (int m = 1; m < 64; m <<= 1) {
    amax = fmaxf(amax, __shfl_xor(amax, m));
    sum += __shfl_xor(sum, m);
  }
  if ((tt & 63) == 0) sred[half][tt >> 6] = make_float2(amax, sum);
  __syncthreads();
  float2 r0 = sred[half][0], r1 = sred[half][1], r2 = sred[half][2],
         r3 = sred[half][3];
  amax = fmaxf(fmaxf(r0.x, r1.x), fmaxf(r2.x, r3.x));
  sum = r0.y + r1.y + r2.y + r3.y;
  const float inv = amax > 0.f ? 127.f / amax : 0.f;
  if (tt == 0) { s[row] = amax / 127.f; rs2[row] = 128.f * sum; }
  int* xo = xq + (size_t)row * (IN_F / 4);
#pragma unroll
  for (int i = 0; i < 4; ++i) {
    int q0 = min(127, max(-127, __float2int_rn(v[i].x * inv)));
    int q1 = min(127, max(-127, __float2int_rn(v[i].y * inv)));
    int q2 = min(127, max(-127, __float2int_rn(v[i].z * inv)));
    int q3 = min(127, max(-127, __float2int_rn(v[i].w * inv)));
    xo[tt + i * 256] = (q0 & 255) | ((q1 & 255) << 8) | ((q2 & 255) << 16) |
                       ((q3 & 255) << 24);
  }
}

#define BAR()    asm volatile("s_barrier" ::: "memory")
#define WAITV3() asm volatile("s_waitcnt vmcnt(3)" ::: "memory")
#define WAITV0() asm volatile("s_waitcnt vmcnt(0)" ::: "memory")
#define SBAR()   __builtin_amdgcn_sched_barrier(0)
#define MFMAI(va, vb, vc) __builtin_amdgcn_mfma_i32_16x16x64_i8((va), (vb), (vc), 0, 0, 0)

// OCCUPANCY-FIRST design, race-fixed: BM=256 x BN=128, BK=64, 8 waves
// (4M x 2N), per-wave output 64x64 (acc=64 regs) -> 4 waves/SIMD budget.
// LDS: 3-DEEP circular buffers (A 3x16KB + B 3x8KB = 72 KB) -> 2 blocks/CU.
// R11's failure: staging t+2 into the SAME buffer being read in the SAME
// inter-barrier region (latency-margin race under setprio wave-skew).
// Fix: stage t+2 into buffer (t+2)%3 whose last readers were iteration t-1 —
// read-completion (MFMA lgkm drain) and the stage issue are separated by the
// end-of-(t-1) barrier. Same hazard-edge class as all passing schedules.
// Per tile: 8 ds_read_b128 + 3 global_load_lds + 16 MFMA + counted-vmcnt + BAR.
// Swizzle (64B rows): phys_granule = logical ^ ((row + (row>>2)) & 3) —
// 2-way max on frag reads (free, m136); linear-dest staging compatible.
__global__ __launch_bounds__(512, 4) void k_gemm_i8(
    const char* __restrict__ Xq, const char* __restrict__ Wq,
    const float* __restrict__ s, const float* __restrict__ rs2,
    const float* __restrict__ bias, float* __restrict__ out) {
  __shared__ __align__(16) char smA[3 * 256 * 64];  // 48 KB
  __shared__ __align__(16) char smB[3 * 128 * 64];  // 24 KB
  const int tid = threadIdx.x;
  const int w = tid >> 6, ln = tid & 63;
  const int wr = w >> 1, wc = w & 1;  // 4M x 2N waves

  // XCD swizzle: 1024 wgs = 8 xcds * 128-chunks (bijective). n in high bits:
  // each XCD's B-slice (4 n-blocks = 2 MB) stays L2-resident.
  const int orig = blockIdx.x;
  const int wg = (orig & 7) * 128 + (orig >> 3);
  const int bm0 = (wg & 31) * 256;
  const int bn0 = (wg >> 5) * 128;

  // staging source (pre-swizzled): lane l -> chunk-row l>>2, logical granule
  // (l&3) ^ f, f = ((l>>2)+(l>>4))&3  [f(full row) collapses per lane]
  const int srow = ln >> 2;
  const int sgr = ((ln & 3) ^ (((ln >> 2) + (ln >> 4)) & 3)) * 16;
  const char* pA = Xq + (size_t)(bm0 + w * 32 + srow) * IN_F + sgr;
  const char* pB = Wq + (size_t)(bn0 + w * 16 + srow) * IN_F + sgr;

  // fragment-read offsets: row = base + l15, logical k-granule = ln>>4,
  // physical = (ln>>4) ^ ((l15+(l15>>2))&3)  [per-lane constant]
  const int l15 = ln & 15;
  const int pg = (((ln >> 4) ^ ((l15 + (l15 >> 2)) & 3))) * 16;
  const int aoff = (wr * 64 + l15) * 64 + pg;  // + i*1024 + bufA
  const int boff = (wc * 64 + l15) * 64 + pg;  // + j*1024 + bufB

#define STAGE(t, oa, ob)                                                       \
  do {                                                                         \
    async16(pA + (size_t)(t)*64, smA + (oa) + w * 2048);                       \
    async16(pA + (size_t)(t)*64 + 16 * IN_F, smA + (oa) + w * 2048 + 1024);    \
    async16(pB + (size_t)(t)*64, smB + (ob) + w * 1024);                       \
  } while (0)

  // prologue: tiles 0,1 staged into bufs 0,1 (6 loads); V3 -> tile0 landed
  STAGE(0, 0, 0);
  STAGE(1, 16384, 8192);
  i32x4 acc[4][4] = {};
  i32x4 a[4], b[4];
  int aCur = 0, aNxt = 16384, aFar = 32768;  // 3-way rotation (uniform)
  int bCur = 0, bNxt = 8192, bFar = 16384;
  WAITV3();
  BAR();

  for (int t = 0; t < NTK; ++t) {
#pragma unroll
    for (int i = 0; i < 4; ++i)
      a[i] = *(const i32x4*)(smA + aCur + aoff + i * 1024);
#pragma unroll
    for (int j = 0; j < 4; ++j)
      b[j] = *(const i32x4*)(smB + bCur + boff + j * 1024);
    if (t + 2 < NTK) STAGE(t + 2, aFar, bFar);
    SBAR();
    __builtin_amdgcn_s_setprio(1);
#pragma unroll
    for (int i = 0; i < 4; ++i)
#pragma unroll
      for (int j = 0; j < 4; ++j) acc[i][j] = MFMAI(a[i], b[j], acc[i][j]);
    __builtin_amdgcn_s_setprio(0);
    if (t < NTK - 2) { WAITV3(); } else { WAITV0(); }
    BAR();
    // rotate buffers: cur <- nxt <- far <- cur
    int ta = aCur; aCur = aNxt; aNxt = aFar; aFar = ta;
    int tb = bCur; bCur = bNxt; bNxt = bFar; bFar = tb;
  }

  // epilogue: C/D 16x16: col=l15, row=(ln>>4)*4+reg.
  // out[row][col] = s[row]*acc + rs2[row] + bias[col]
  const int r4 = (ln >> 4) * 4;
#pragma unroll
  for (int i = 0; i < 4; ++i) {
    const int rowb = bm0 + wr * 64 + i * 16 + r4;
    float sv[4], rv[4];
#pragma unroll
    for (int r = 0; r < 4; ++r) { sv[r] = s[rowb + r]; rv[r] = rs2[rowb + r]; }
#pragma unroll
    for (int j = 0; j < 4; ++j) {
      const int col = bn0 + wc * 64 + j * 16 + l15;
      const float bv = bias[col];
#pragma unroll
      for (int r = 0; r < 4; ++r)
        out[(size_t)(rowb + r) * OUT_F + col] =
            fmaf(sv[r], (float)acc[i][j][r], rv[r] + bv);
    }
  }
#undef STAGE
}

// Fallback: one thread per output element
__global__ void k_naive(const float* __restrict__ x, const int* __restrict__ table,
                        const int* __restrict__ codes, const float* __restrict__ bias,
                        float* __restrict__ out) {
  __shared__ float sx[IN_F];
  const int m = blockIdx.y;
  const int n = blockIdx.x * 256 + threadIdx.x;
  for (int k = threadIdx.x; k < IN_F; k += 256) sx[k] = x[(size_t)m * IN_F + k];
  __syncthreads();
  float sacc = 0.f;
  const int* cr = codes + (size_t)n * (IN_F / 4);
  for (int k4 = 0; k4 < IN_F / 4; ++k4) {
    int code = cr[k4];
    int4 tt = *(const int4*)(table + (size_t)code * 4);
    const float* xp = sx + k4 * 4;
    sacc += xp[0] * tt.x + xp[1] * tt.y + xp[2] * tt.z + xp[3] * tt.w;
  }
  out[(size_t)m * OUT_F + n] = sacc + bias[n];
}

extern "C" void kernel_launch(void* const* d_in, const int* in_sizes, int n_in,
                              void* d_out, int out_size, void* d_ws, size_t ws_size,
                              hipStream_t stream) {
  const float* x = (const float*)d_in[0];
  const int* table = (const int*)d_in[1];
  const int* codes = (const int*)d_in[2];
  const float* bias = (const float*)d_in[3];
  float* out = (float*)d_out;

  const size_t wqb = (size_t)OUT_F * IN_F;      // 16.75 MB
  const size_t xqb = (size_t)M_DIM * IN_F;      // 33.5 MB
  const size_t sb = (size_t)M_DIM * 4;          // 32 KB
  if (ws_size >= wqb + xqb + 2 * sb) {
    char* Wq = (char*)d_ws;
    char* Xq = (char*)d_ws + wqb;
    float* sS = (float*)((char*)d_ws + wqb + xqb);
    float* sR = sS + M_DIM;
    // 4096 quantize blocks (2 rows each) + 2048 decompress blocks (512 thr)
    const int prep_blocks = M_DIM / 2 + (OUT_F * IN_F / 16) / 512;
    k_prep<<<prep_blocks, 512, 0, stream>>>(x, codes, table, (int*)Xq, sS, sR,
                                            (int*)Wq);
    k_gemm_i8<<<dim3((M_DIM / 256) * (OUT_F / 128)), dim3(512), 0, stream>>>(
        Xq, Wq, sS, sR, bias, out);
  } else {
    dim3 grid(OUT_F / 256, M_DIM);
    k_naive<<<grid, 256, 0, stream>>>(x, table, codes, bias, out);
  }
}

// Round 13
// 178.165 us; speedup vs baseline: 1.2666x; 1.2666x over previous
//
#include <hip/hip_runtime.h>

#define IN_F 4096
#define OUT_F 4096
#define M_DIM 8192  // 4 * 2048
#define NT 32       // K tiles of 128 (i8)

typedef __attribute__((ext_vector_type(4))) int i32x4;

typedef const __attribute__((address_space(1))) void* gas_t;
typedef __attribute__((address_space(3))) void* las_t;

__device__ __forceinline__ void async16(const void* g, void* s) {
  __builtin_amdgcn_global_load_lds((gas_t)g, (las_t)s, 16, 0, 0);
}

// ---- fused prep, 512-thread blocks:
//   blocks [0,4096):    quantize 2 x-rows per block (256 threads each half)
//   blocks [4096,6144): decompress 2048 code-quads per block (4 codes/thread)
// quantize: xq=i8 per-row (s=absmax/127), rs2=128*rowsum (exact f32 term)
// decompress: codes -> packed i8 (w-128 == w^0x80)
__global__ __launch_bounds__(512) void k_prep(
    const float* __restrict__ x, const int* __restrict__ codes,
    const int* __restrict__ table, int* __restrict__ xq,
    float* __restrict__ s, float* __restrict__ rs2, int* __restrict__ Wq) {
  const int bid = blockIdx.x, t = threadIdx.x;
  if (bid >= M_DIM / 2) {  // ---- decompress path
    int i = (bid - M_DIM / 2) * 512 + t;  // quad index
    int4 c = *(const int4*)(codes + (size_t)i * 4);
    int4 t0 = *(const int4*)(table + (size_t)c.x * 4);
    int4 t1 = *(const int4*)(table + (size_t)c.y * 4);
    int4 t2 = *(const int4*)(table + (size_t)c.z * 4);
    int4 t3 = *(const int4*)(table + (size_t)c.w * 4);
    int4 o;
    o.x = (t0.x | (t0.y << 8) | (t0.z << 16) | (t0.w << 24)) ^ 0x80808080;
    o.y = (t1.x | (t1.y << 8) | (t1.z << 16) | (t1.w << 24)) ^ 0x80808080;
    o.z = (t2.x | (t2.y << 8) | (t2.z << 16) | (t2.w << 24)) ^ 0x80808080;
    o.w = (t3.x | (t3.y << 8) | (t3.z << 16) | (t3.w << 24)) ^ 0x80808080;
    *(int4*)(Wq + (size_t)i * 4) = o;
    return;
  }
  // ---- quantize path: half = row parity, 256 threads per row
  __shared__ float2 sred[2][4];
  const int half = t >> 8, tt = t & 255;
  const int row = bid * 2 + half;
  const float4* xr = (const float4*)(x + (size_t)row * IN_F);
  float4 v[4];
  float amax = 0.f, sum = 0.f;
#pragma unroll
  for (int i = 0; i < 4; ++i) {
    v[i] = xr[tt + i * 256];
    amax = fmaxf(amax, fmaxf(fmaxf(fabsf(v[i].x), fabsf(v[i].y)),
                             fmaxf(fabsf(v[i].z), fabsf(v[i].w))));
    sum += v[i].x + v[i].y + v[i].z + v[i].w;
  }
#pragma unroll
  for (int m = 1; m < 64; m <<= 1) {
    amax = fmaxf(amax, __shfl_xor(amax, m));
    sum += __shfl_xor(sum, m);
  }
  if ((tt & 63) == 0) sred[half][tt >> 6] = make_float2(amax, sum);
  __syncthreads();
  float2 r0 = sred[half][0], r1 = sred[half][1], r2 = sred[half][2],
         r3 = sred[half][3];
  amax = fmaxf(fmaxf(r0.x, r1.x), fmaxf(r2.x, r3.x));
  sum = r0.y + r1.y + r2.y + r3.y;
  const float inv = amax > 0.f ? 127.f / amax : 0.f;
  if (tt == 0) { s[row] = amax / 127.f; rs2[row] = 128.f * sum; }
  int* xo = xq + (size_t)row * (IN_F / 4);
#pragma unroll
  for (int i = 0; i < 4; ++i) {
    int q0 = min(127, max(-127, __float2int_rn(v[i].x * inv)));
    int q1 = min(127, max(-127, __float2int_rn(v[i].y * inv)));
    int q2 = min(127, max(-127, __float2int_rn(v[i].z * inv)));
    int q3 = min(127, max(-127, __float2int_rn(v[i].w * inv)));
    xo[tt + i * 256] = (q0 & 255) | ((q1 & 255) << 8) | ((q2 & 255) << 16) |
                       ((q3 & 255) << 24);
  }
}

#define BAR()    asm volatile("s_barrier" ::: "memory")
#define WAITV6() asm volatile("s_waitcnt vmcnt(6)" ::: "memory")
#define WAITV4() asm volatile("s_waitcnt vmcnt(4)" ::: "memory")
#define WAITV0() asm volatile("s_waitcnt vmcnt(0)" ::: "memory")
#define SBAR()   __builtin_amdgcn_sched_barrier(0)
#define MFMAI(va, vb, vc) __builtin_amdgcn_mfma_i32_16x16x64_i8((va), (vb), (vc), 0, 0, 0)

// 256x256 tile, BK=128 i8, 8 waves (2Mx4N), 4-phase counted-vmcnt schedule,
// one-phase-ahead LDS->reg reads, 16x16x64 MFMA (conflict-free geometry:
// 128B rows + granule XOR (row&7), full 8-granule span — 0 conflicts
// measured R5/R6/R8/R10; all deviations (R4 32x32, R12 64B-row mod-4)
// measured >1e7 conflicts). ROUND-6 SCHEDULE — best measured (127.6us).
// Structural map (measured): R7 2-barrier -4%; R9 merged-phase null;
// R11 same-buffer stage race (fails); R12 small-tile 2-blocks/CU -38%
// (FETCH 149->503MB — intensity dominates occupancy on this problem).
// 1 block/CU, 2 waves/SIMD is the register-bound fixed point: 128-acc/wave
// output tile is required for intensity, and caps waves at 2/SIMD.
__global__ __launch_bounds__(512, 2) void k_gemm_i8(
    const char* __restrict__ Xq, const char* __restrict__ Wq,
    const float* __restrict__ s, const float* __restrict__ rs2,
    const float* __restrict__ bias, float* __restrict__ out) {
  extern __shared__ char sm[];
  const int tid = threadIdx.x;
  const int w = tid >> 6, ln = tid & 63;
  const int wr = w >> 2, wc = w & 3;

  const int orig = blockIdx.x;
  const int wg = (orig & 7) * 64 + (orig >> 3);  // XCD swizzle (512%8==0)
  const int bm0 = (wg >> 4) * 256;
  const int bn0 = (wg & 15) * 256;

  // staging source (pre-swizzled): lane l -> row (l>>3), granule (l&7)^(l>>3)
  const int srow = ln >> 3;
  const int sg = ((ln & 7) ^ srow) * 16;
  const char* pA = Xq + (size_t)(bm0 + w * 16 + srow) * IN_F + sg;
  const char* pB = Wq + (size_t)(bn0 + w * 16 + srow) * IN_F + sg;
  const int wso = w * 2048;

  // fragment-read offsets: 16x16x64: row=l&15, k-granule ks*4+(l>>4),
  // physical granule = logical ^ (row&7), row&7 == ln&7.
  const int l15 = ln & 15;
  int ccp[2];
#pragma unroll
  for (int ks = 0; ks < 2; ++ks)
    ccp[ks] = ((ks * 4 + (ln >> 4)) ^ (ln & 7)) * 16;
  const int arow = (wr * 64 + l15) * 128;           // + i*2048 + base
  const int brow = 65536 + (wc * 32 + l15) * 128;   // + bn*2048 + base

#define STA(t, h, db)                                                          \
  do {                                                                         \
    async16(pA + (size_t)(t)*128 + (size_t)(h)*128 * IN_F,                     \
            sm + (db)*32768 + (h)*16384 + wso);                                \
    async16(pA + (size_t)(t)*128 + (size_t)(h)*128 * IN_F + 8 * IN_F,          \
            sm + (db)*32768 + (h)*16384 + wso + 1024);                         \
  } while (0)
#define STB(t, h, db)                                                          \
  do {                                                                         \
    async16(pB + (size_t)(t)*128 + (size_t)(h)*128 * IN_F,                     \
            sm + 65536 + (db)*32768 + (h)*16384 + wso);                        \
    async16(pB + (size_t)(t)*128 + (size_t)(h)*128 * IN_F + 8 * IN_F,          \
            sm + 65536 + (db)*32768 + (h)*16384 + wso + 1024);                 \
  } while (0)
#define RD_A0(base)                                                            \
  do {                                                                         \
    _Pragma("unroll") for (int i = 0; i < 4; ++i)                              \
        _Pragma("unroll") for (int ks = 0; ks < 2; ++ks) a0[i][ks] =           \
        *(const i32x4*)(sm + (base) + arow + i * 2048 + ccp[ks]);              \
  } while (0)
#define RD_A1(base)                                                            \
  do {                                                                         \
    _Pragma("unroll") for (int i = 0; i < 4; ++i)                              \
        _Pragma("unroll") for (int ks = 0; ks < 2; ++ks) a1[i][ks] =           \
        *(const i32x4*)(sm + (base) + arow + i * 2048 + ccp[ks]);              \
  } while (0)
#define RD_B0(base)                                                            \
  do {                                                                         \
    _Pragma("unroll") for (int bn = 0; bn < 2; ++bn)                           \
        _Pragma("unroll") for (int ks = 0; ks < 2; ++ks) b0[bn][ks] =          \
        *(const i32x4*)(sm + (base) + brow + bn * 2048 + ccp[ks]);             \
  } while (0)
#define RD_B1(base)                                                            \
  do {                                                                         \
    _Pragma("unroll") for (int bn = 0; bn < 2; ++bn)                           \
        _Pragma("unroll") for (int ks = 0; ks < 2; ++ks) b1[bn][ks] =          \
        *(const i32x4*)(sm + (base) + brow + bn * 2048 + ccp[ks]);             \
  } while (0)

  // prologue: tile0 full + tile1 {Ah0,Bh0,Bh1}; V4 drains through STA(1,0)
  STA(0, 0, 0); STB(0, 0, 0); STB(0, 1, 0); STA(0, 1, 0);
  STA(1, 0, 1); STB(1, 0, 1); STB(1, 1, 1);
  i32x4 acc[8][4] = {};
  i32x4 a0[4][2], a1[4][2], b0[2][2], b1[2][2];
  WAITV4();
  BAR();
  RD_A0(0);
  RD_B0(0);

  for (int t = 0; t < NT; ++t) {
    const int d = t & 1, dn = d ^ 1;
    const int d32 = d * 32768, dn32 = dn * 32768;
    // ---- p1: read b1 <- B(d,h1); stage (t+1)A h1 -> dn; MFMA a0 x b0; BAR
    RD_B1(d32 + 16384);
    if (t + 1 < NT) STA(t + 1, 1, dn);
    SBAR();
    __builtin_amdgcn_s_setprio(1);
#pragma unroll
    for (int i = 0; i < 4; ++i)
#pragma unroll
      for (int bn = 0; bn < 2; ++bn) {
        acc[i][bn] = MFMAI(a0[i][0], b0[bn][0], acc[i][bn]);
        acc[i][bn] = MFMAI(a0[i][1], b0[bn][1], acc[i][bn]);
      }
    __builtin_amdgcn_s_setprio(0);
    BAR();  // p1-end: a0/b0 regions now safely overwritable
    // ---- p2: read a1 <- A(d,h1); stage (t+2)A h0 -> d; MFMA a0 x b1 (no BAR)
    RD_A1(d32 + 16384);
    if (t + 2 < NT) STA(t + 2, 0, d);
    SBAR();
    __builtin_amdgcn_s_setprio(1);
#pragma unroll
    for (int i = 0; i < 4; ++i)
#pragma unroll
      for (int bn = 0; bn < 2; ++bn) {
        acc[i][2 + bn] = MFMAI(a0[i][0], b1[bn][0], acc[i][2 + bn]);
        acc[i][2 + bn] = MFMAI(a0[i][1], b1[bn][1], acc[i][2 + bn]);
      }
    __builtin_amdgcn_s_setprio(0);
    // ---- p3: read a0' <- A(dn,h0) (t+1); stage (t+2)B h0 -> d; MFMA a1 x b1;
    //          V6 drains B(t+1,h0/h1); BAR publishes
    if (t + 1 < NT) RD_A0(dn32);
    if (t + 2 < NT) STB(t + 2, 0, d);
    SBAR();
    __builtin_amdgcn_s_setprio(1);
#pragma unroll
    for (int i = 0; i < 4; ++i)
#pragma unroll
      for (int bn = 0; bn < 2; ++bn) {
        acc[4 + i][2 + bn] = MFMAI(a1[i][0], b1[bn][0], acc[4 + i][2 + bn]);
        acc[4 + i][2 + bn] = MFMAI(a1[i][1], b1[bn][1], acc[4 + i][2 + bn]);
      }
    __builtin_amdgcn_s_setprio(0);
    if (t < NT - 2) { WAITV6(); } else { WAITV0(); }
    BAR();  // p3-end
    // ---- p4: stage (t+2)B h1 -> d; MFMA a1 x b0; read b0' <- B(dn,h0)
    //          (AFTER MFMA: register WAR on b0); V4 drains A(t+1,h1)+A(t+2,h0)
    if (t + 2 < NT) STB(t + 2, 1, d);
    SBAR();
    __builtin_amdgcn_s_setprio(1);
#pragma unroll
    for (int i = 0; i < 4; ++i)
#pragma unroll
      for (int bn = 0; bn < 2; ++bn) {
        acc[4 + i][bn] = MFMAI(a1[i][0], b0[bn][0], acc[4 + i][bn]);
        acc[4 + i][bn] = MFMAI(a1[i][1], b0[bn][1], acc[4 + i][bn]);
      }
    __builtin_amdgcn_s_setprio(0);
    if (t + 1 < NT) RD_B0(dn32);
    if (t < NT - 2) { WAITV4(); } else { WAITV0(); }
    BAR();  // p4-end
  }

  // epilogue: C/D 16x16: col=l&15, row=(l>>4)*4+reg.
  // out[row][col] = s[row]*acc + rs2[row] + bias[col]
  const int r4 = (ln >> 4) * 4;
#pragma unroll
  for (int im = 0; im < 8; ++im) {
    const int mq = im >> 2, i = im & 3;
    const int rowb = bm0 + mq * 128 + wr * 64 + i * 16 + r4;
    float sv[4], rv[4];
#pragma unroll
    for (int r = 0; r < 4; ++r) { sv[r] = s[rowb + r]; rv[r] = rs2[rowb + r]; }
#pragma unroll
    for (int in = 0; in < 4; ++in) {
      const int nq = in >> 1, bn = in & 1;
      const int col = bn0 + nq * 128 + wc * 32 + bn * 16 + l15;
      const float bv = bias[col];
#pragma unroll
      for (int r = 0; r < 4; ++r)
        out[(size_t)(rowb + r) * OUT_F + col] =
            fmaf(sv[r], (float)acc[im][in][r], rv[r] + bv);
    }
  }
#undef STA
#undef STB
#undef RD_A0
#undef RD_A1
#undef RD_B0
#undef RD_B1
}

// Fallback: one thread per output element
__global__ void k_naive(const float* __restrict__ x, const int* __restrict__ table,
                        const int* __restrict__ codes, const float* __restrict__ bias,
                        float* __restrict__ out) {
  __shared__ float sx[IN_F];
  const int m = blockIdx.y;
  const int n = blockIdx.x * 256 + threadIdx.x;
  for (int k = threadIdx.x; k < IN_F; k += 256) sx[k] = x[(size_t)m * IN_F + k];
  __syncthreads();
  float sacc = 0.f;
  const int* cr = codes + (size_t)n * (IN_F / 4);
  for (int k4 = 0; k4 < IN_F / 4; ++k4) {
    int code = cr[k4];
    int4 tt = *(const int4*)(table + (size_t)code * 4);
    const float* xp = sx + k4 * 4;
    sacc += xp[0] * tt.x + xp[1] * tt.y + xp[2] * tt.z + xp[3] * tt.w;
  }
  out[(size_t)m * OUT_F + n] = sacc + bias[n];
}

extern "C" void kernel_launch(void* const* d_in, const int* in_sizes, int n_in,
                              void* d_out, int out_size, void* d_ws, size_t ws_size,
                              hipStream_t stream) {
  const float* x = (const float*)d_in[0];
  const int* table = (const int*)d_in[1];
  const int* codes = (const int*)d_in[2];
  const float* bias = (const float*)d_in[3];
  float* out = (float*)d_out;

  const size_t wqb = (size_t)OUT_F * IN_F;      // 16.75 MB
  const size_t xqb = (size_t)M_DIM * IN_F;      // 33.5 MB
  const size_t sb = (size_t)M_DIM * 4;          // 32 KB
  if (ws_size >= wqb + xqb + 2 * sb) {
    char* Wq = (char*)d_ws;
    char* Xq = (char*)d_ws + wqb;
    float* sS = (float*)((char*)d_ws + wqb + xqb);
    float* sR = sS + M_DIM;
    // 4096 quantize blocks (2 rows each) + 2048 decompress blocks (512 thr)
    const int prep_blocks = M_DIM / 2 + (OUT_F * IN_F / 16) / 512;
    k_prep<<<prep_blocks, 512, 0, stream>>>(x, codes, table, (int*)Xq, sS, sR,
                                            (int*)Wq);
    (void)hipFuncSetAttribute((const void*)k_gemm_i8,
                              hipFuncAttributeMaxDynamicSharedMemorySize, 131072);
    k_gemm_i8<<<dim3((M_DIM / 256) * (OUT_F / 256)), dim3(512), 131072, stream>>>(
        Xq, Wq, sS, sR, bias, out);
  } else {
    dim3 grid(OUT_F / 256, M_DIM);
    k_naive<<<grid, 256, 0, stream>>>(x, table, codes, bias, out);
  }
}